// Round 12
// baseline (159.312 us; speedup 1.0000x reference)
//
#include <hip/hip_runtime.h>
#include <hip/hip_bf16.h>

// LearnableDiffusionContrastiveLoss on MI355X.
// Algebra: l2norm(dm_normalized @ z) == l2norm(dm @ z) (positive row scaling
// cancels) -> skip the 10-step normalization entirely.
// R12 = R7 with B taken OFF the LDS pipe: B fragments load straight from the
// L2-resident packed zp into registers (per-lane contiguous by construction),
// issued before A's global loads so their waitcnt doesn't drain A. Only A
// uses LDS (R7's conflict-free path). LDS bytes/block-step 112KB -> 40KB.
// Theory: R7's plateau is the CU LDS pipe (~85 B/cyc), not the memory fabric.

typedef float f32x4 __attribute__((ext_vector_type(4)));
typedef short s16x8 __attribute__((ext_vector_type(8)));

#define NN 8192
#define DFF 256
#define NNEG 10

__device__ __forceinline__ unsigned short f2bf(float x) {
  return __builtin_bit_cast(unsigned short, __float2bfloat16(x));
}

__device__ __forceinline__ float bf2f(unsigned short u) {
  return __builtin_bit_cast(float, (unsigned int)u << 16);
}

__device__ __forceinline__ float dot4(float4 a, float4 b) {
  return a.x * b.x + a.y * b.y + a.z * b.z + a.w * b.w;
}

// ---- pack z [8192][256] f32 -> zp bf16 [kchunk 256][kw 4][col 256][ke 8] -----
// zp elem offset(k,d) = (k>>5)*8192 + ((k>>3)&3)*2048 + d*8 + (k&7)
// B-frag(kw, col0) = 16 lanes x 16B contiguous -> direct coalesced global load.
__global__ void k_pack(const float* __restrict__ z,
                       unsigned short* __restrict__ zp) {
  __shared__ float tile[64][65];
  const int bx = blockIdx.x;  // k tile 0..127
  const int by = blockIdx.y;  // d tile 0..3
  const int t = threadIdx.x;
  const int lc = t & 63, lq = t >> 6;  // 0..3
#pragma unroll
  for (int p = 0; p < 16; ++p) {
    const int kr = lq * 16 + p;
    tile[kr][lc] = z[(size_t)(bx * 64 + kr) * DFF + by * 64 + lc];
  }
  __syncthreads();
#pragma unroll
  for (int p2 = 0; p2 < 2; ++p2) {
    const int ko = lq * 2 + p2;  // k-octet within tile, 0..7
    s16x8 v;
#pragma unroll
    for (int ke = 0; ke < 8; ++ke) v[ke] = (short)f2bf(tile[ko * 8 + ke][lc]);
    const int chunk = bx * 2 + (ko >> 2);
    const int kw = ko & 3;
    const int d = by * 64 + lc;
    *(s16x8*)(zp + (size_t)chunk * 8192 + kw * 2048 + d * 8) = v;
  }
}

// ---- GEMM: part[ks] = dm[mtile, ks-slice] @ z  (BM=128, BN=256, BK=32) -------
// 512 thr / 8 waves, wave (wm,wn) = (w>>2, w&3) owns rows [wm*64,+64) x cols
// [wn*64,+64): 4x4 16x16x32 frags.
//   A: global f32 (coalesced) -> regs -> bf16 -> LDS dbuf (R7 layout, clean).
//   B: global bf16 zp -> REGISTERS directly (L2-resident; no LDS bounce).
__global__ __launch_bounds__(512, 4) void k_gemm(const float* __restrict__ dm,
                                                 const unsigned short* __restrict__ zp,
                                                 unsigned short* __restrict__ part,
                                                 int KS) {
  __shared__ __align__(16) unsigned short sA[2][4096];  // 2 x 8 KB
  const int bx = blockIdx.x;
  const int mtile = bx & 63;  // 64 mtiles of 128 rows
  const int ks = bx >> 6;
  const int klen = NN / KS;
  const int k0 = ks * klen;
  const int c0 = k0 >> 5;       // first K-chunk
  const int steps = klen / 32;  // 32 for KS=8
  const int tid = threadIdx.x;
  const int w = tid >> 6;
  const int l = tid & 63;
  const int m0 = mtile * 128;

  // A staging: thread owns 8 consecutive k of one row (2 float4 -> 1 s16x8)
  const int arow = w * 16 + (l & 15);  // 0..127
  const int akw = l >> 4;              // 0..3
  const float* asrc = dm + (size_t)(m0 + arow) * NN + k0 + akw * 8;

  const int r16 = l & 15, kw = l >> 4;
  const int wm = w >> 2, wn = w & 3;

  // B direct-load base: lane-constant offset within each 16KB K-chunk
  const unsigned short* bbase = zp + (size_t)c0 * 8192 + kw * 2048 + (wn * 64 + r16) * 8;

  f32x4 acc[4][4] = {};
  f32x4 a0, a1;
  s16x8 bfr[4];

#define LOAD_B(t_)                                                           \
  {                                                                          \
    const unsigned short* bp_ = bbase + (size_t)(t_)*8192;                   \
    _Pragma("unroll") for (int nj = 0; nj < 4; ++nj)                         \
        bfr[nj] = *(const s16x8*)(bp_ + nj * 128);                           \
  }

#define LOAD_A(t_)                                                           \
  {                                                                          \
    a0 = *(const f32x4*)(asrc + (t_)*32);                                    \
    a1 = *(const f32x4*)(asrc + (t_)*32 + 4);                                \
  }

#define WRITE_A(s_)                                                         \
  {                                                                         \
    s16x8 h_;                                                               \
    h_[0] = (short)f2bf(a0[0]); h_[1] = (short)f2bf(a0[1]);                 \
    h_[2] = (short)f2bf(a0[2]); h_[3] = (short)f2bf(a0[3]);                 \
    h_[4] = (short)f2bf(a1[0]); h_[5] = (short)f2bf(a1[1]);                 \
    h_[6] = (short)f2bf(a1[2]); h_[7] = (short)f2bf(a1[3]);                 \
    *(s16x8*)&sA[s_][akw * 1024 + arow * 8] = h_;                           \
  }

#define COMPUTE(s_)                                                         \
  {                                                                         \
    s16x8 af[4];                                                            \
    _Pragma("unroll") for (int mi = 0; mi < 4; ++mi) {                      \
      const int row_ = wm * 64 + mi * 16 + r16;                             \
      af[mi] = *(const s16x8*)&sA[s_][kw * 1024 + row_ * 8];                \
    }                                                                       \
    _Pragma("unroll") for (int mi = 0; mi < 4; ++mi)                        \
      _Pragma("unroll") for (int nj = 0; nj < 4; ++nj)                      \
        acc[mi][nj] = __builtin_amdgcn_mfma_f32_16x16x32_bf16(              \
            af[mi], bfr[nj], acc[mi][nj], 0, 0, 0);                         \
  }

  // prologue: stage A(0)
  LOAD_A(0);
  WRITE_A(0);
  __syncthreads();

  for (int t = 0; t < steps; ++t) {
    const int cur = t & 1, nxt = cur ^ 1;
    LOAD_B(t);  // issue B FIRST: its wait won't force-drain the newer A loads
    if (t + 1 < steps) LOAD_A(t + 1);
    COMPUTE(cur);
    if (t + 1 < steps) WRITE_A(nxt);
    __syncthreads();
  }

#undef LOAD_B
#undef LOAD_A
#undef WRITE_A
#undef COMPUTE

  // epilogue: C/D layout col=lane&15, row=(lane>>4)*4+reg [verified m89/m91]
  unsigned short* cb = part + (size_t)ks * NN * DFF;
#pragma unroll
  for (int mi = 0; mi < 4; ++mi)
#pragma unroll
    for (int nj = 0; nj < 4; ++nj) {
      const int col = wn * 64 + nj * 16 + r16;
      const int row0 = m0 + wm * 64 + mi * 16 + kw * 4;
#pragma unroll
      for (int r = 0; r < 4; ++r)
        cb[(size_t)(row0 + r) * DFF + col] = f2bf(acc[mi][nj][r]);
    }
}

// ---- fused loss: neg norms, K-split partial sum (bf16), norms, LSE -----------
__global__ __launch_bounds__(256) void k_loss(const float* __restrict__ z,
                                              const unsigned short* __restrict__ part,
                                              const int* __restrict__ neg_idx,
                                              float* __restrict__ lpart, int KS) {
  __shared__ float sneg[NNEG * DFF];
  __shared__ float swsum[4];
  const int t = threadIdx.x;
  const int w = t >> 6, l = t & 63;
  for (int k = w; k < NNEG; k += 4) {
    const int idx = neg_idx[k];
    float4 v = *(const float4*)(z + (size_t)idx * DFF + l * 4);
    float ss = dot4(v, v);
#pragma unroll
    for (int off = 32; off > 0; off >>= 1) ss += __shfl_xor(ss, off);
    const float s = 1.0f / fmaxf(sqrtf(ss), 1e-12f);
    float4 o;
    o.x = v.x * s; o.y = v.y * s; o.z = v.z * s; o.w = v.w * s;
    *(float4*)&sneg[k * DFF + l * 4] = o;
  }
  __syncthreads();
  const int gw = blockIdx.x * 4 + w;  // 0..1023, 8 rows each
  float lsum = 0.f;
  for (int rr = 0; rr < 8; ++rr) {
    const int i = gw * 8 + rr;
    const float4 a = *(const float4*)(z + (size_t)i * DFF + l * 4);
    float4 p; p.x = 0.f; p.y = 0.f; p.z = 0.f; p.w = 0.f;
    for (int ksp = 0; ksp < KS; ++ksp) {
      const ushort4 q =
          *(const ushort4*)(part + ((size_t)ksp * NN + i) * DFF + l * 4);
      p.x += bf2f(q.x); p.y += bf2f(q.y); p.z += bf2f(q.z); p.w += bf2f(q.w);
    }
    float vals[13];
    vals[0] = dot4(a, a);
    vals[1] = dot4(p, p);
    vals[2] = dot4(a, p);
#pragma unroll
    for (int k = 0; k < NNEG; ++k) {
      const float4 nv = *(const float4*)&sneg[k * DFF + l * 4];
      vals[3 + k] = dot4(a, nv);
    }
#pragma unroll
    for (int off = 32; off > 0; off >>= 1)
#pragma unroll
      for (int j = 0; j < 13; ++j) vals[j] += __shfl_xor(vals[j], off);
    const float na = fmaxf(sqrtf(vals[0]), 1e-12f);
    const float npp = fmaxf(sqrtf(vals[1]), 1e-12f);
    const float ps = vals[2] / (na * npp) * 5.0f;  // 1/TEMP
    float S = 0.f;
#pragma unroll
    for (int k = 0; k < NNEG; ++k) S += expf(vals[3 + k] / na * 5.0f);
    lsum += logf(expf(ps) + S) - ps;
  }
  if (l == 0) swsum[w] = lsum;
  __syncthreads();
  if (t == 0) lpart[blockIdx.x] = swsum[0] + swsum[1] + swsum[2] + swsum[3];
}

__global__ void k_final(const float* __restrict__ lpart, float* __restrict__ out) {
  const int t = threadIdx.x;  // 64
  float v = lpart[t] + lpart[t + 64] + lpart[t + 128] + lpart[t + 192];
#pragma unroll
  for (int off = 32; off > 0; off >>= 1) v += __shfl_xor(v, off);
  if (t == 0) out[0] = v * (1.0f / (float)NN);
}

extern "C" void kernel_launch(void* const* d_in, const int* in_sizes, int n_in,
                              void* d_out, int out_size, void* d_ws, size_t ws_size,
                              hipStream_t stream) {
  const float* z = (const float*)d_in[0];
  const float* dm = (const float*)d_in[1];
  // d_in[2] edge_index, d_in[3] reliable_negatives: unused by the forward pass
  const int* neg_idx = (const int*)d_in[4];
  float* out = (float*)d_out;

  // workspace: zp (4MB) | partials bf16 (KS*4MB) | lpart (1KB)
  const size_t ZP = (size_t)NN * DFF * 2;  // 4 MB
  auto need = [ZP](size_t ks) { return ZP + ks * (size_t)NN * DFF * 2 + 1024; };
  int KS = 8;
  if (ws_size < need(8)) KS = (ws_size >= need(4)) ? 4 : 2;

  char* ws = (char*)d_ws;
  unsigned short* zp = (unsigned short*)ws;
  unsigned short* part = (unsigned short*)(ws + ZP);
  float* lpart = (float*)(ws + ZP + (size_t)KS * NN * DFF * 2);

  k_pack<<<dim3(128, 4), 256, 0, stream>>>(z, zp);
  k_gemm<<<64 * KS, 512, 0, stream>>>(dm, zp, part, KS);
  k_loss<<<256, 256, 0, stream>>>(z, part, neg_idx, lpart, KS);
  k_final<<<1, 64, 0, stream>>>(lpart, out);
}

// Round 13
// 141.915 us; speedup vs baseline: 1.1226x; 1.1226x over previous
//
#include <hip/hip_runtime.h>
#include <hip/hip_bf16.h>

// LearnableDiffusionContrastiveLoss on MI355X.
// Algebra: l2norm(dm_normalized @ z) == l2norm(dm @ z) (positive row scaling
// cancels) -> skip the 10-step normalization entirely.
// R13 = R7 traffic (BM=128, 544MB staged) + R4's drain-free counted-vmcnt
// schedule (T3/T4): A(t+2)->regs and B(t+2)->3-slot gload_lds ring issued
// each step; s_waitcnt vmcnt(4) (never 0) + raw s_barrier. No vmcnt(0) drain
// in the main loop -> full-iteration latency cover for both operands.
// R4 proved this schedule sustains 6.4 TB/s aggregate staging; R7's
// __syncthreads drain only reached 5.4.

typedef float f32x4 __attribute__((ext_vector_type(4)));
typedef short s16x8 __attribute__((ext_vector_type(8)));

#define NN 8192
#define DFF 256
#define NNEG 10

__device__ __forceinline__ unsigned short f2bf(float x) {
  return __builtin_bit_cast(unsigned short, __float2bfloat16(x));
}

__device__ __forceinline__ float bf2f(unsigned short u) {
  return __builtin_bit_cast(float, (unsigned int)u << 16);
}

__device__ __forceinline__ void gload_lds16(const void* g, void* l) {
  __builtin_amdgcn_global_load_lds(
      (const __attribute__((address_space(1))) void*)(void*)g,
      (__attribute__((address_space(3))) void*)l, 16, 0, 0);
}

__device__ __forceinline__ float dot4(float4 a, float4 b) {
  return a.x * b.x + a.y * b.y + a.z * b.z + a.w * b.w;
}

// ---- pack z [8192][256] f32 -> zp bf16 [kchunk 256][kw 4][col 256][ke 8] -----
// zp elem offset(k,d) = (k>>5)*8192 + ((k>>3)&3)*2048 + d*8 + (k&7)
// so each GEMM K-step (32 k x 256 d) is one contiguous 16KB chunk.
__global__ void k_pack(const float* __restrict__ z,
                       unsigned short* __restrict__ zp) {
  __shared__ float tile[64][65];
  const int bx = blockIdx.x;  // k tile 0..127
  const int by = blockIdx.y;  // d tile 0..3
  const int t = threadIdx.x;
  const int lc = t & 63, lq = t >> 6;  // 0..3
#pragma unroll
  for (int p = 0; p < 16; ++p) {
    const int kr = lq * 16 + p;
    tile[kr][lc] = z[(size_t)(bx * 64 + kr) * DFF + by * 64 + lc];
  }
  __syncthreads();
#pragma unroll
  for (int p2 = 0; p2 < 2; ++p2) {
    const int ko = lq * 2 + p2;  // k-octet within tile, 0..7
    s16x8 v;
#pragma unroll
    for (int ke = 0; ke < 8; ++ke) v[ke] = (short)f2bf(tile[ko * 8 + ke][lc]);
    const int chunk = bx * 2 + (ko >> 2);
    const int kw = ko & 3;
    const int d = by * 64 + lc;
    *(s16x8*)(zp + (size_t)chunk * 8192 + kw * 2048 + d * 8) = v;
  }
}

// ---- GEMM: part[ks] = dm[mtile, ks-slice] @ z  (BM=128, BN=256, BK=32) -------
// 512 thr / 8 waves, wave (wm,wn) = (w>>2, w&3) owns rows [wm*64,+64) x cols
// [wn*64,+64): 4x4 16x16x32 frags.
//   sA: dbuf 2 x [kw 4][row 128][ke 8] bf16 8KB (reg-staged f32->bf16)
//   sB: ring 3 x [kw 4][col 256][ke 8] bf16 16KB (gload_lds, byte-linear)
// Schedule per step t: {issue A(t+2)->regs, B(t+2)->ring} COMPUTE(t)
//   vmcnt(4) [= step t+2 stays in flight] WRITE_A(t+1) lgkm(0) s_barrier.
__global__ __launch_bounds__(512, 4) void k_gemm(const float* __restrict__ dm,
                                                 const unsigned short* __restrict__ zp,
                                                 unsigned short* __restrict__ part,
                                                 int KS) {
  __shared__ __align__(16) unsigned short sA[2][4096];  // 2 x 8 KB
  __shared__ __align__(16) unsigned short sB[3][8192];  // 3 x 16 KB
  const int bx = blockIdx.x;
  const int mtile = bx & 63;  // 64 mtiles of 128 rows
  const int ks = bx >> 6;
  const int klen = NN / KS;
  const int k0 = ks * klen;
  const int c0 = k0 >> 5;       // first K-chunk
  const int steps = klen / 32;  // 32 for KS=8 (even, >=4)
  const int tid = threadIdx.x;
  const int w = tid >> 6;
  const int l = tid & 63;
  const int m0 = mtile * 128;

  // A staging: thread owns 8 consecutive k of one row (2 float4 -> 1 s16x8)
  const int arow = w * 16 + (l & 15);  // 0..127
  const int akw = l >> 4;              // 0..3
  const float* asrc = dm + (size_t)(m0 + arow) * NN + k0 + akw * 8;

  const int r16 = l & 15, kw = l >> 4;
  const int wm = w >> 2, wn = w & 3;

  f32x4 acc[4][4] = {};
  // two static A-reg sets (rule #20: compile-time selection via unroll-2)
  f32x4 aS0x, aS0y, aS1x, aS1y;

#define LOAD_A_TO(t_, rx_, ry_)                                              \
  {                                                                          \
    rx_ = *(const f32x4*)(asrc + (t_)*32);                                   \
    ry_ = *(const f32x4*)(asrc + (t_)*32 + 4);                               \
  }

#define STAGE_B(t_)                                                         \
  {                                                                         \
    const unsigned short* cs_ = zp + (size_t)(c0 + (t_)) * 8192;            \
    _Pragma("unroll") for (int q = 0; q < 2; ++q) {                         \
      const int piece_ = w * 2 + q; /* 0..15, 1KB each */                   \
      gload_lds16((const char*)(cs_ + piece_ * 512) + l * 16,               \
                  (char*)sB[(t_) % 3] + piece_ * 1024);                     \
    }                                                                       \
  }

#define WRITE_A_FROM(s_, rx_, ry_)                                         \
  {                                                                        \
    s16x8 h_;                                                              \
    h_[0] = (short)f2bf(rx_[0]); h_[1] = (short)f2bf(rx_[1]);              \
    h_[2] = (short)f2bf(rx_[2]); h_[3] = (short)f2bf(rx_[3]);              \
    h_[4] = (short)f2bf(ry_[0]); h_[5] = (short)f2bf(ry_[1]);              \
    h_[6] = (short)f2bf(ry_[2]); h_[7] = (short)f2bf(ry_[3]);              \
    *(s16x8*)&sA[s_][akw * 1024 + arow * 8] = h_;                          \
  }

#define COMPUTE(t_)                                                        \
  {                                                                        \
    const unsigned short* sa_ = sA[(t_)&1];                                \
    const unsigned short* sb_ = sB[(t_) % 3];                              \
    s16x8 af[4], bfr[4];                                                   \
    _Pragma("unroll") for (int mi = 0; mi < 4; ++mi) {                     \
      const int row_ = wm * 64 + mi * 16 + r16;                            \
      af[mi] = *(const s16x8*)&sa_[kw * 1024 + row_ * 8];                  \
    }                                                                      \
    _Pragma("unroll") for (int nj = 0; nj < 4; ++nj) {                     \
      const int col_ = wn * 64 + nj * 16 + r16;                            \
      bfr[nj] = *(const s16x8*)&sb_[kw * 2048 + col_ * 8];                 \
    }                                                                      \
    _Pragma("unroll") for (int mi = 0; mi < 4; ++mi)                       \
      _Pragma("unroll") for (int nj = 0; nj < 4; ++nj)                     \
        acc[mi][nj] = __builtin_amdgcn_mfma_f32_16x16x32_bf16(             \
            af[mi], bfr[nj], acc[mi][nj], 0, 0, 0);                        \
  }

  // STEP body: load->(set for t+2), write<-(set holding t+1)
#define STEP(t_, LRX, LRY, WRX, WRY)                                       \
  {                                                                        \
    if ((t_) + 2 < steps) {                                                \
      LOAD_A_TO((t_) + 2, LRX, LRY);                                       \
      STAGE_B((t_) + 2);                                                   \
    }                                                                      \
    COMPUTE(t_);                                                           \
    if ((t_) + 2 < steps) {                                                \
      asm volatile("s_waitcnt vmcnt(4)" ::: "memory");                     \
    } else {                                                               \
      asm volatile("s_waitcnt vmcnt(0)" ::: "memory");                     \
    }                                                                      \
    __builtin_amdgcn_sched_barrier(0);                                     \
    if ((t_) + 1 < steps) { WRITE_A_FROM(((t_) + 1) & 1, WRX, WRY); }      \
    asm volatile("s_waitcnt lgkmcnt(0)" ::: "memory");                     \
    __builtin_amdgcn_sched_barrier(0);                                     \
    __builtin_amdgcn_s_barrier();                                          \
    __builtin_amdgcn_sched_barrier(0);                                     \
  }

  // prologue: issue steps 0 and 1; complete 0; keep 1 in flight
  LOAD_A_TO(0, aS0x, aS0y);
  STAGE_B(0);
  LOAD_A_TO(1, aS1x, aS1y);
  STAGE_B(1);
  asm volatile("s_waitcnt vmcnt(4)" ::: "memory");  // A(0),B(0) done
  __builtin_amdgcn_sched_barrier(0);
  WRITE_A_FROM(0, aS0x, aS0y);
  asm volatile("s_waitcnt lgkmcnt(0)" ::: "memory");
  __builtin_amdgcn_sched_barrier(0);
  __builtin_amdgcn_s_barrier();
  __builtin_amdgcn_sched_barrier(0);

  for (int t = 0; t < steps; t += 2) {
    STEP(t, aS0x, aS0y, aS1x, aS1y);      // even: load t+2 -> set0, write t+1 from set1
    STEP(t + 1, aS1x, aS1y, aS0x, aS0y);  // odd:  load t+3 -> set1, write t+2 from set0
  }

#undef LOAD_A_TO
#undef STAGE_B
#undef WRITE_A_FROM
#undef COMPUTE
#undef STEP

  // epilogue: C/D layout col=lane&15, row=(lane>>4)*4+reg [verified m89/m91]
  unsigned short* cb = part + (size_t)ks * NN * DFF;
#pragma unroll
  for (int mi = 0; mi < 4; ++mi)
#pragma unroll
    for (int nj = 0; nj < 4; ++nj) {
      const int col = wn * 64 + nj * 16 + r16;
      const int row0 = m0 + wm * 64 + mi * 16 + kw * 4;
#pragma unroll
      for (int r = 0; r < 4; ++r)
        cb[(size_t)(row0 + r) * DFF + col] = f2bf(acc[mi][nj][r]);
    }
}

// ---- fused loss: neg norms, K-split partial sum (bf16), norms, LSE -----------
__global__ __launch_bounds__(256) void k_loss(const float* __restrict__ z,
                                              const unsigned short* __restrict__ part,
                                              const int* __restrict__ neg_idx,
                                              float* __restrict__ lpart, int KS) {
  __shared__ float sneg[NNEG * DFF];
  __shared__ float swsum[4];
  const int t = threadIdx.x;
  const int w = t >> 6, l = t & 63;
  for (int k = w; k < NNEG; k += 4) {
    const int idx = neg_idx[k];
    float4 v = *(const float4*)(z + (size_t)idx * DFF + l * 4);
    float ss = dot4(v, v);
#pragma unroll
    for (int off = 32; off > 0; off >>= 1) ss += __shfl_xor(ss, off);
    const float s = 1.0f / fmaxf(sqrtf(ss), 1e-12f);
    float4 o;
    o.x = v.x * s; o.y = v.y * s; o.z = v.z * s; o.w = v.w * s;
    *(float4*)&sneg[k * DFF + l * 4] = o;
  }
  __syncthreads();
  const int gw = blockIdx.x * 4 + w;  // 0..1023, 8 rows each
  float lsum = 0.f;
  for (int rr = 0; rr < 8; ++rr) {
    const int i = gw * 8 + rr;
    const float4 a = *(const float4*)(z + (size_t)i * DFF + l * 4);
    float4 p; p.x = 0.f; p.y = 0.f; p.z = 0.f; p.w = 0.f;
    for (int ksp = 0; ksp < KS; ++ksp) {
      const ushort4 q =
          *(const ushort4*)(part + ((size_t)ksp * NN + i) * DFF + l * 4);
      p.x += bf2f(q.x); p.y += bf2f(q.y); p.z += bf2f(q.z); p.w += bf2f(q.w);
    }
    float vals[13];
    vals[0] = dot4(a, a);
    vals[1] = dot4(p, p);
    vals[2] = dot4(a, p);
#pragma unroll
    for (int k = 0; k < NNEG; ++k) {
      const float4 nv = *(const float4*)&sneg[k * DFF + l * 4];
      vals[3 + k] = dot4(a, nv);
    }
#pragma unroll
    for (int off = 32; off > 0; off >>= 1)
#pragma unroll
      for (int j = 0; j < 13; ++j) vals[j] += __shfl_xor(vals[j], off);
    const float na = fmaxf(sqrtf(vals[0]), 1e-12f);
    const float npp = fmaxf(sqrtf(vals[1]), 1e-12f);
    const float ps = vals[2] / (na * npp) * 5.0f;  // 1/TEMP
    float S = 0.f;
#pragma unroll
    for (int k = 0; k < NNEG; ++k) S += expf(vals[3 + k] / na * 5.0f);
    lsum += logf(expf(ps) + S) - ps;
  }
  if (l == 0) swsum[w] = lsum;
  __syncthreads();
  if (t == 0) lpart[blockIdx.x] = swsum[0] + swsum[1] + swsum[2] + swsum[3];
}

__global__ void k_final(const float* __restrict__ lpart, float* __restrict__ out) {
  const int t = threadIdx.x;  // 64
  float v = lpart[t] + lpart[t + 64] + lpart[t + 128] + lpart[t + 192];
#pragma unroll
  for (int off = 32; off > 0; off >>= 1) v += __shfl_xor(v, off);
  if (t == 0) out[0] = v * (1.0f / (float)NN);
}

extern "C" void kernel_launch(void* const* d_in, const int* in_sizes, int n_in,
                              void* d_out, int out_size, void* d_ws, size_t ws_size,
                              hipStream_t stream) {
  const float* z = (const float*)d_in[0];
  const float* dm = (const float*)d_in[1];
  // d_in[2] edge_index, d_in[3] reliable_negatives: unused by the forward pass
  const int* neg_idx = (const int*)d_in[4];
  float* out = (float*)d_out;

  // workspace: zp (4MB) | partials bf16 (KS*4MB) | lpart (1KB)
  const size_t ZP = (size_t)NN * DFF * 2;  // 4 MB
  auto need = [ZP](size_t ks) { return ZP + ks * (size_t)NN * DFF * 2 + 1024; };
  int KS = 8;
  if (ws_size < need(8)) KS = (ws_size >= need(4)) ? 4 : 2;

  char* ws = (char*)d_ws;
  unsigned short* zp = (unsigned short*)ws;
  unsigned short* part = (unsigned short*)(ws + ZP);
  float* lpart = (float*)(ws + ZP + (size_t)KS * NN * DFF * 2);

  k_pack<<<dim3(128, 4), 256, 0, stream>>>(z, zp);
  k_gemm<<<64 * KS, 512, 0, stream>>>(dm, zp, part, KS);
  k_loss<<<256, 256, 0, stream>>>(z, part, neg_idx, lpart, KS);
  k_final<<<1, 64, 0, stream>>>(lpart, out);
}

// Round 14
// 129.400 us; speedup vs baseline: 1.2312x; 1.0967x over previous
//
#include <hip/hip_runtime.h>
#include <hip/hip_bf16.h>

// LearnableDiffusionContrastiveLoss on MI355X.
// Algebra: l2norm(dm_normalized @ z) == l2norm(dm @ z) (positive row scaling
// cancels) -> skip the 10-step normalization entirely.
// R14: zero VMEM->VGPR returns in the GEMM hot loop. A (raw f32 dm) staged
// via global_load_lds with XOR-swizzled SOURCE (linear LDS dest, rule #21);
// waves ds_read f32 frags (conflict-free swizzle) and cvt_pk in-register.
// B via gload_lds as before (R7). Hypothesis: the ~20-25 B/cyc/CU ingest
// plateau of R1-R13 is the VMEM register-return path; gload_lds bypasses it
// (m97-family GEMMs ingest ~53 B/cyc/CU using gload_lds for both operands).

typedef float f32x4 __attribute__((ext_vector_type(4)));
typedef short s16x8 __attribute__((ext_vector_type(8)));

#define NN 8192
#define DFF 256
#define NNEG 10

__device__ __forceinline__ unsigned short f2bf(float x) {
  return __builtin_bit_cast(unsigned short, __float2bfloat16(x));
}

__device__ __forceinline__ float bf2f(unsigned short u) {
  return __builtin_bit_cast(float, (unsigned int)u << 16);
}

__device__ __forceinline__ void gload_lds16(const void* g, void* l) {
  __builtin_amdgcn_global_load_lds(
      (const __attribute__((address_space(1))) void*)(void*)g,
      (__attribute__((address_space(3))) void*)l, 16, 0, 0);
}

__device__ __forceinline__ float dot4(float4 a, float4 b) {
  return a.x * b.x + a.y * b.y + a.z * b.z + a.w * b.w;
}

// ---- pack z [8192][256] f32 -> zp bf16 [kchunk 256][kw 4][col 256][ke 8] -----
// zp elem offset(k,d) = (k>>5)*8192 + ((k>>3)&3)*2048 + d*8 + (k&7)
// so each GEMM K-step (32 k x 256 d) is one contiguous 16KB chunk.
__global__ void k_pack(const float* __restrict__ z,
                       unsigned short* __restrict__ zp) {
  __shared__ float tile[64][65];
  const int bx = blockIdx.x;  // k tile 0..127
  const int by = blockIdx.y;  // d tile 0..3
  const int t = threadIdx.x;
  const int lc = t & 63, lq = t >> 6;  // 0..3
#pragma unroll
  for (int p = 0; p < 16; ++p) {
    const int kr = lq * 16 + p;
    tile[kr][lc] = z[(size_t)(bx * 64 + kr) * DFF + by * 64 + lc];
  }
  __syncthreads();
#pragma unroll
  for (int p2 = 0; p2 < 2; ++p2) {
    const int ko = lq * 2 + p2;  // k-octet within tile, 0..7
    s16x8 v;
#pragma unroll
    for (int ke = 0; ke < 8; ++ke) v[ke] = (short)f2bf(tile[ko * 8 + ke][lc]);
    const int chunk = bx * 2 + (ko >> 2);
    const int kw = ko & 3;
    const int d = by * 64 + lc;
    *(s16x8*)(zp + (size_t)chunk * 8192 + kw * 2048 + d * 8) = v;
  }
}

// ---- GEMM: part[ks] = dm[mtile, ks-slice] @ z  (BM=128, BN=256, BK=32) -------
// 512 thr / 8 waves, wave (wm,wn)=(w>>2,w&3) owns rows [wm*64,+64) x cols
// [wn*64,+64): 4x4 16x16x32 frags. LDS dbuf 64KB:
//   sA: 2 x [kw 4][256 slots x 16B] raw f32 16KB. Slot s' holds global chunk
//       s = s' ^ ((s'>>3)&7)  (chunk s = (row = s>>1, half = s&1)).
//       gload_lds: linear dest, swizzled per-lane SOURCE (rule #21).
//       Frag read at s' = s ^ ((s>>3)&7): verified 8 words/bank (free).
//   sB: 2 x [kw 4][col 256][ke 8] bf16 16KB (= zp chunk, byte-linear).
// NO global->VGPR loads in the loop; cvt f32->bf16 happens per-wave from LDS.
__global__ __launch_bounds__(512, 4) void k_gemm(const float* __restrict__ dm,
                                                 const unsigned short* __restrict__ zp,
                                                 unsigned short* __restrict__ part,
                                                 int KS) {
  __shared__ __align__(16) char sA[2][16384];
  __shared__ __align__(16) unsigned short sB[2][8192];
  const int bx = blockIdx.x;
  const int mtile = bx & 63;  // 64 mtiles of 128 rows
  const int ks = bx >> 6;
  const int klen = NN / KS;
  const int k0 = ks * klen;
  const int c0 = k0 >> 5;       // first K-chunk
  const int steps = klen / 32;  // 32 for KS=8
  const int tid = threadIdx.x;
  const int w = tid >> 6;
  const int l = tid & 63;
  const int m0 = mtile * 128;

  const int r16 = l & 15, kw = l >> 4;
  const int wm = w >> 2, wn = w & 3;

  // A staging precompute: two gloads per wave, o = 16B-unit LDS index
  const int o0 = w * 128 + l, o1 = o0 + 64;
  const int kws0 = o0 >> 8, sp0 = o0 & 255;
  const int kws1 = o1 >> 8, sp1 = o1 & 255;
  const int s0 = sp0 ^ ((sp0 >> 3) & 7);
  const int s1 = sp1 ^ ((sp1 >> 3) & 7);
  // global source for chunk s in section kws: dm[m0 + (s>>1)][k0 + kws*8 + (s&1)*4]
  const float* a0src =
      dm + (size_t)(m0 + (s0 >> 1)) * NN + k0 + kws0 * 8 + (s0 & 1) * 4;
  const float* a1src =
      dm + (size_t)(m0 + (s1 >> 1)) * NN + k0 + kws1 * 8 + (s1 & 1) * 4;

  f32x4 acc[4][4] = {};

#define STAGE_A(t_, s_)                                                      \
  {                                                                          \
    gload_lds16(a0src + (t_)*32, sA[s_] + o0 * 16);                          \
    gload_lds16(a1src + (t_)*32, sA[s_] + o1 * 16);                          \
  }

#define STAGE_B(t_, s_)                                                      \
  {                                                                          \
    const unsigned short* cs_ = zp + (size_t)(c0 + (t_)) * 8192;             \
    _Pragma("unroll") for (int q = 0; q < 2; ++q) {                          \
      const int piece_ = w * 2 + q; /* 0..15, 1KB each */                    \
      gload_lds16((const char*)(cs_ + piece_ * 512) + l * 16,                \
                  (char*)sB[s_] + piece_ * 1024);                            \
    }                                                                        \
  }

#define COMPUTE(s_)                                                          \
  {                                                                          \
    s16x8 af[4], bfr[4];                                                     \
    _Pragma("unroll") for (int mi = 0; mi < 4; ++mi) {                       \
      const int row_ = wm * 64 + mi * 16 + r16; /* 0..127 */                 \
      const int m_ = (row_ >> 2) & 7;                                        \
      const int sa_ = (2 * row_) ^ m_;  /* slot of half0 */                  \
      const int sb2_ = sa_ ^ 1;         /* slot of half1 */                  \
      const f32x4 x0 = *(const f32x4*)(sA[s_] + kw * 4096 + sa_ * 16);       \
      const f32x4 x1 = *(const f32x4*)(sA[s_] + kw * 4096 + sb2_ * 16);      \
      s16x8 h_;                                                              \
      h_[0] = (short)f2bf(x0[0]); h_[1] = (short)f2bf(x0[1]);                \
      h_[2] = (short)f2bf(x0[2]); h_[3] = (short)f2bf(x0[3]);                \
      h_[4] = (short)f2bf(x1[0]); h_[5] = (short)f2bf(x1[1]);                \
      h_[6] = (short)f2bf(x1[2]); h_[7] = (short)f2bf(x1[3]);                \
      af[mi] = h_;                                                           \
    }                                                                        \
    _Pragma("unroll") for (int nj = 0; nj < 4; ++nj) {                       \
      const int col_ = wn * 64 + nj * 16 + r16;                              \
      bfr[nj] = *(const s16x8*)&sB[s_][kw * 2048 + col_ * 8];                \
    }                                                                        \
    _Pragma("unroll") for (int mi = 0; mi < 4; ++mi)                         \
      _Pragma("unroll") for (int nj = 0; nj < 4; ++nj)                       \
        acc[mi][nj] = __builtin_amdgcn_mfma_f32_16x16x32_bf16(               \
            af[mi], bfr[nj], acc[mi][nj], 0, 0, 0);                          \
  }

  // prologue
  STAGE_A(0, 0);
  STAGE_B(0, 0);
  __syncthreads();  // drains vmcnt(0): step 0 staged

  for (int t = 0; t < steps; ++t) {
    const int cur = t & 1, nxt = cur ^ 1;
    if (t + 1 < steps) {
      STAGE_A(t + 1, nxt);
      STAGE_B(t + 1, nxt);
    }
    COMPUTE(cur);
    __syncthreads();  // all reads of cur done + stage(t+1) landed
  }

#undef STAGE_A
#undef STAGE_B
#undef COMPUTE

  // epilogue: C/D layout col=lane&15, row=(lane>>4)*4+reg [verified m89/m91]
  unsigned short* cb = part + (size_t)ks * NN * DFF;
#pragma unroll
  for (int mi = 0; mi < 4; ++mi)
#pragma unroll
    for (int nj = 0; nj < 4; ++nj) {
      const int col = wn * 64 + nj * 16 + r16;
      const int row0 = m0 + wm * 64 + mi * 16 + kw * 4;
#pragma unroll
      for (int r = 0; r < 4; ++r)
        cb[(size_t)(row0 + r) * DFF + col] = f2bf(acc[mi][nj][r]);
    }
}

// ---- fused loss: neg norms, K-split partial sum (bf16), norms, LSE -----------
__global__ __launch_bounds__(256) void k_loss(const float* __restrict__ z,
                                              const unsigned short* __restrict__ part,
                                              const int* __restrict__ neg_idx,
                                              float* __restrict__ lpart, int KS) {
  __shared__ float sneg[NNEG * DFF];
  __shared__ float swsum[4];
  const int t = threadIdx.x;
  const int w = t >> 6, l = t & 63;
  for (int k = w; k < NNEG; k += 4) {
    const int idx = neg_idx[k];
    float4 v = *(const float4*)(z + (size_t)idx * DFF + l * 4);
    float ss = dot4(v, v);
#pragma unroll
    for (int off = 32; off > 0; off >>= 1) ss += __shfl_xor(ss, off);
    const float s = 1.0f / fmaxf(sqrtf(ss), 1e-12f);
    float4 o;
    o.x = v.x * s; o.y = v.y * s; o.z = v.z * s; o.w = v.w * s;
    *(float4*)&sneg[k * DFF + l * 4] = o;
  }
  __syncthreads();
  const int gw = blockIdx.x * 4 + w;  // 0..1023, 8 rows each
  float lsum = 0.f;
  for (int rr = 0; rr < 8; ++rr) {
    const int i = gw * 8 + rr;
    const float4 a = *(const float4*)(z + (size_t)i * DFF + l * 4);
    float4 p; p.x = 0.f; p.y = 0.f; p.z = 0.f; p.w = 0.f;
    for (int ksp = 0; ksp < KS; ++ksp) {
      const ushort4 q =
          *(const ushort4*)(part + ((size_t)ksp * NN + i) * DFF + l * 4);
      p.x += bf2f(q.x); p.y += bf2f(q.y); p.z += bf2f(q.z); p.w += bf2f(q.w);
    }
    float vals[13];
    vals[0] = dot4(a, a);
    vals[1] = dot4(p, p);
    vals[2] = dot4(a, p);
#pragma unroll
    for (int k = 0; k < NNEG; ++k) {
      const float4 nv = *(const float4*)&sneg[k * DFF + l * 4];
      vals[3 + k] = dot4(a, nv);
    }
#pragma unroll
    for (int off = 32; off > 0; off >>= 1)
#pragma unroll
      for (int j = 0; j < 13; ++j) vals[j] += __shfl_xor(vals[j], off);
    const float na = fmaxf(sqrtf(vals[0]), 1e-12f);
    const float npp = fmaxf(sqrtf(vals[1]), 1e-12f);
    const float ps = vals[2] / (na * npp) * 5.0f;  // 1/TEMP
    float S = 0.f;
#pragma unroll
    for (int k = 0; k < NNEG; ++k) S += expf(vals[3 + k] / na * 5.0f);
    lsum += logf(expf(ps) + S) - ps;
  }
  if (l == 0) swsum[w] = lsum;
  __syncthreads();
  if (t == 0) lpart[blockIdx.x] = swsum[0] + swsum[1] + swsum[2] + swsum[3];
}

__global__ void k_final(const float* __restrict__ lpart, float* __restrict__ out) {
  const int t = threadIdx.x;  // 64
  float v = lpart[t] + lpart[t + 64] + lpart[t + 128] + lpart[t + 192];
#pragma unroll
  for (int off = 32; off > 0; off >>= 1) v += __shfl_xor(v, off);
  if (t == 0) out[0] = v * (1.0f / (float)NN);
}

extern "C" void kernel_launch(void* const* d_in, const int* in_sizes, int n_in,
                              void* d_out, int out_size, void* d_ws, size_t ws_size,
                              hipStream_t stream) {
  const float* z = (const float*)d_in[0];
  const float* dm = (const float*)d_in[1];
  // d_in[2] edge_index, d_in[3] reliable_negatives: unused by the forward pass
  const int* neg_idx = (const int*)d_in[4];
  float* out = (float*)d_out;

  // workspace: zp (4MB) | partials bf16 (KS*4MB) | lpart (1KB)
  const size_t ZP = (size_t)NN * DFF * 2;  // 4 MB
  auto need = [ZP](size_t ks) { return ZP + ks * (size_t)NN * DFF * 2 + 1024; };
  int KS = 8;
  if (ws_size < need(8)) KS = (ws_size >= need(4)) ? 4 : 2;

  char* ws = (char*)d_ws;
  unsigned short* zp = (unsigned short*)ws;
  unsigned short* part = (unsigned short*)(ws + ZP);
  float* lpart = (float*)(ws + ZP + (size_t)KS * NN * DFF * 2);

  k_pack<<<dim3(128, 4), 256, 0, stream>>>(z, zp);
  k_gemm<<<64 * KS, 512, 0, stream>>>(dm, zp, part, KS);
  k_loss<<<256, 256, 0, stream>>>(z, part, neg_idx, lpart, KS);
  k_final<<<1, 64, 0, stream>>>(lpart, out);
}